// Round 1
// baseline (1934.043 us; speedup 1.0000x reference)
//
#include <hip/hip_runtime.h>
#include <math.h>

#define IH 1024
#define IW 1024
#define NPIX (IH * IW)

// ---------------- Stage 1: grayscale ----------------
// gray = 0.2989*R + 0.587*G + 0.114*B, accumulated left-to-right with
// separately-rounded mul/add (no fma) to mimic plain numpy evaluation.
__global__ void k_gray(const float* __restrict__ x, float* __restrict__ gray) {
    int i = blockIdx.x * blockDim.x + threadIdx.x;
    if (i >= NPIX) return;
    float r = x[i];
    float g = x[NPIX + i];
    float b = x[2 * NPIX + i];
    float t = __fadd_rn(__fmul_rn(r, 0.2989f), __fmul_rn(g, 0.587f));
    gray[i] = __fadd_rn(t, __fmul_rn(b, 0.114f));
}

// ---------------- Stage 2: Sobel -> mag + direction bucket ----------------
__global__ void k_sobel(const float* __restrict__ gray,
                        float* __restrict__ mag,
                        unsigned char* __restrict__ bucket) {
    int idx = blockIdx.x * blockDim.x + threadIdx.x;
    if (idx >= NPIX) return;
    int i = idx / IW;
    int j = idx - i * IW;

    // zero-padded neighborhood
    float a00 = 0.f, a01 = 0.f, a02 = 0.f;
    float a10 = 0.f,              a12 = 0.f;
    float a20 = 0.f, a21 = 0.f, a22 = 0.f;
    bool up = (i > 0), dn = (i < IH - 1), lf = (j > 0), rt = (j < IW - 1);
    if (up && lf) a00 = gray[idx - IW - 1];
    if (up)       a01 = gray[idx - IW];
    if (up && rt) a02 = gray[idx - IW + 1];
    if (lf)       a10 = gray[idx - 1];
    if (rt)       a12 = gray[idx + 1];
    if (dn && lf) a20 = gray[idx + IW - 1];
    if (dn)       a21 = gray[idx + IW];
    if (dn && rt) a22 = gray[idx + IW + 1];

    // KX = [[-1,0,1],[-2,0,2],[-1,0,1]]  (cross-correlation), row-major accumulation
    float gx = __fmul_rn(-1.f, a00);
    gx = __fadd_rn(gx, a02);
    gx = __fadd_rn(gx, __fmul_rn(-2.f, a10));
    gx = __fadd_rn(gx, __fmul_rn(2.f, a12));
    gx = __fadd_rn(gx, __fmul_rn(-1.f, a20));
    gx = __fadd_rn(gx, a22);

    // KY = [[1,2,1],[0,0,0],[-1,-2,-1]]
    float gy = a00;
    gy = __fadd_rn(gy, __fmul_rn(2.f, a01));
    gy = __fadd_rn(gy, a02);
    gy = __fadd_rn(gy, __fmul_rn(-1.f, a20));
    gy = __fadd_rn(gy, __fmul_rn(-2.f, a21));
    gy = __fadd_rn(gy, __fmul_rn(-1.f, a22));

    float m = __fsqrt_rn(__fadd_rn(__fmul_rn(gx, gx), __fmul_rn(gy, gy)));
    mag[idx] = m;

    float ai = __fmul_rn(atan2f(gy, gx), 57.295779513082320876798154814105f);
    unsigned char bk;
    if (ai < -22.5f || ai >= 157.5f)      bk = 0;  // horizontal compare
    else if (ai < 22.5f)                  bk = 1;  // vertical compare
    else if (ai < 67.5f)                  bk = 2;  // diag (-1,-1)/(1,1)
    else if (ai < 112.5f)                 bk = 3;  // vertical compare
    else                                  bk = 4;  // anti-diag (-1,1)/(1,-1)
    bucket[idx] = bk;
}

// ---------------- Stage 3: NMS + double threshold ----------------
// strong (0/1 float) -> d_out; weak (0/1 u8) -> ws
__global__ void k_nms(const float* __restrict__ mag,
                      const unsigned char* __restrict__ bucket,
                      float* __restrict__ strong,
                      unsigned char* __restrict__ weak) {
    int idx = blockIdx.x * blockDim.x + threadIdx.x;
    if (idx >= NPIX) return;
    int i = idx / IW;
    int j = idx - i * IW;
    if (i == 0 || i == IH - 1 || j == 0 || j == IW - 1) {
        strong[idx] = 0.f;
        weak[idx] = 0;
        return;
    }
    float c = mag[idx];
    float n1, n2;
    switch (bucket[idx]) {
        case 0:  n1 = mag[idx - 1];       n2 = mag[idx + 1];       break;
        case 2:  n1 = mag[idx - IW - 1];  n2 = mag[idx + IW + 1];  break;
        case 4:  n1 = mag[idx - IW + 1];  n2 = mag[idx + IW - 1];  break;
        default: n1 = mag[idx - IW];      n2 = mag[idx + IW];      break; // buckets 1,3
    }
    bool keep = (c >= n1) && (c >= n2);
    float supp = keep ? c : 0.f;
    bool s = (supp >= 50.f);
    bool w = (supp >= 20.f) && !s;
    strong[idx] = s ? 1.f : 0.f;
    weak[idx] = w ? 1 : 0;
}

// ---------------- Stage 4: sequential hysteresis tracking ----------------
// Exactly replicates the reference raster scan:
//   out[j] = S[j] | (W[j] & (seed[j] | out[j-1]))
// seed[j] = OR(prevU[j-1..j+1], S[j], S[j+1], nxt[j-1..j+1])
// Row recurrence resolved per-row with ballot + Kogge-Stone carry-lookahead.
__global__ __launch_bounds__(1024) void k_track(float* __restrict__ s,
                                                const unsigned char* __restrict__ weak) {
    __shared__ float sP[IW];  // updated row i-1
    __shared__ float sC[IW];  // original strong row i
    __shared__ float sN[IW];  // original strong row i+1
    __shared__ unsigned long long aggG[16], aggP[16];

    const int j = threadIdx.x;
    const int wv = j >> 6;
    const int ln = j & 63;

    sP[j] = s[j];            // row 0 (border, never updated)
    sC[j] = s[IW + j];       // row 1
    float nxt_val = s[2 * IW + j];
    unsigned char wk_val = weak[IW + j];

    for (int i = 1; i <= IH - 2; ++i) {
        sN[j] = nxt_val;
        // prefetch next row's data (static arrays; hides global latency)
        float nv = 0.f;
        unsigned char wkn = 0;
        if (i < IH - 2) {
            nv = s[(i + 2) * IW + j];        // rows > i+1 not yet modified
            wkn = weak[(i + 1) * IW + j];
        }
        __syncthreads();  // barrier 1: sP/sC/sN consistent

        const bool interior = (j >= 1) && (j <= IW - 2);
        const bool Sb = (sC[j] != 0.f);
        bool p = false;
        bool g = Sb;
        if (interior) {
            bool seed = (sP[j - 1] != 0.f) | (sP[j] != 0.f) | (sP[j + 1] != 0.f)
                      | Sb | (sC[j + 1] != 0.f)
                      | (sN[j - 1] != 0.f) | (sN[j] != 0.f) | (sN[j + 1] != 0.f);
            p = (wk_val != 0);
            g = Sb | (p & seed);
        }

        unsigned long long Gm = __ballot(g);
        unsigned long long Pm = __ballot(p);
        // Kogge-Stone: resolve out[j] = g[j] | p[j]&out[j-1] within the 64-bit word
        #pragma unroll
        for (int k = 1; k <= 32; k <<= 1) {
            Gm |= Pm & (Gm << k);
            Pm &= (Pm << k);
        }
        if (ln == 0) { aggG[wv] = Gm; aggP[wv] = Pm; }
        __syncthreads();  // barrier 2: aggregates visible; all sP/sC/sN reads done

        // sequential carry across the 16 words (cheap, redundant per thread)
        bool c = false;
        for (int t = 0; t < wv; ++t) {
            bool gw = (aggG[t] >> 63) & 1ull;
            bool pw = (aggP[t] >> 63) & 1ull;
            c = gw | (pw & c);
        }
        unsigned long long outm = Gm | (Pm & (c ? ~0ull : 0ull));
        float outf = ((outm >> ln) & 1ull) ? 1.f : 0.f;

        s[i * IW + j] = outf;
        sP[j] = outf;       // own index only: no cross-thread race before next barrier
        sC[j] = sN[j];      // own index only
        nxt_val = nv;
        wk_val = wkn;
    }
}

extern "C" void kernel_launch(void* const* d_in, const int* in_sizes, int n_in,
                              void* d_out, int out_size, void* d_ws, size_t ws_size,
                              hipStream_t stream) {
    const float* x = (const float*)d_in[0];
    float* out = (float*)d_out;
    char* ws = (char*)d_ws;

    float* gray          = (float*)(ws);
    float* mag           = (float*)(ws + 4u * 1024u * 1024u);
    unsigned char* bkt   = (unsigned char*)(ws + 8u * 1024u * 1024u);
    unsigned char* weak  = (unsigned char*)(ws + 9u * 1024u * 1024u);

    dim3 blk(256);
    dim3 grd((NPIX + 255) / 256);
    k_gray<<<grd, blk, 0, stream>>>(x, gray);
    k_sobel<<<grd, blk, 0, stream>>>(gray, mag, bkt);
    k_nms<<<grd, blk, 0, stream>>>(mag, bkt, out, weak);
    k_track<<<1, 1024, 0, stream>>>(out, weak);
}

// Round 2
// 447.791 us; speedup vs baseline: 4.3191x; 4.3191x over previous
//
#include <hip/hip_runtime.h>
#include <math.h>

#define IH 1024
#define IW 1024
#define NPIX (IH * IW)
#define WPR 16  // 64-bit words per row (1024 / 64)

// ---------------- Stage 1: grayscale ----------------
__global__ void k_gray(const float* __restrict__ x, float* __restrict__ gray) {
    int i = blockIdx.x * blockDim.x + threadIdx.x;
    if (i >= NPIX) return;
    float r = x[i];
    float g = x[NPIX + i];
    float b = x[2 * NPIX + i];
    float t = __fadd_rn(__fmul_rn(r, 0.2989f), __fmul_rn(g, 0.587f));
    gray[i] = __fadd_rn(t, __fmul_rn(b, 0.114f));
}

// ---------------- Stage 2: Sobel -> mag + direction bucket ----------------
__global__ void k_sobel(const float* __restrict__ gray,
                        float* __restrict__ mag,
                        unsigned char* __restrict__ bucket) {
    int idx = blockIdx.x * blockDim.x + threadIdx.x;
    if (idx >= NPIX) return;
    int i = idx >> 10;
    int j = idx & (IW - 1);

    float a00 = 0.f, a01 = 0.f, a02 = 0.f;
    float a10 = 0.f,              a12 = 0.f;
    float a20 = 0.f, a21 = 0.f, a22 = 0.f;
    bool up = (i > 0), dn = (i < IH - 1), lf = (j > 0), rt = (j < IW - 1);
    if (up && lf) a00 = gray[idx - IW - 1];
    if (up)       a01 = gray[idx - IW];
    if (up && rt) a02 = gray[idx - IW + 1];
    if (lf)       a10 = gray[idx - 1];
    if (rt)       a12 = gray[idx + 1];
    if (dn && lf) a20 = gray[idx + IW - 1];
    if (dn)       a21 = gray[idx + IW];
    if (dn && rt) a22 = gray[idx + IW + 1];

    float gx = __fmul_rn(-1.f, a00);
    gx = __fadd_rn(gx, a02);
    gx = __fadd_rn(gx, __fmul_rn(-2.f, a10));
    gx = __fadd_rn(gx, __fmul_rn(2.f, a12));
    gx = __fadd_rn(gx, __fmul_rn(-1.f, a20));
    gx = __fadd_rn(gx, a22);

    float gy = a00;
    gy = __fadd_rn(gy, __fmul_rn(2.f, a01));
    gy = __fadd_rn(gy, a02);
    gy = __fadd_rn(gy, __fmul_rn(-1.f, a20));
    gy = __fadd_rn(gy, __fmul_rn(-2.f, a21));
    gy = __fadd_rn(gy, __fmul_rn(-1.f, a22));

    float m = __fsqrt_rn(__fadd_rn(__fmul_rn(gx, gx), __fmul_rn(gy, gy)));
    mag[idx] = m;

    float ai = __fmul_rn(atan2f(gy, gx), 57.295779513082320876798154814105f);
    unsigned char bk;
    if (ai < -22.5f || ai >= 157.5f)      bk = 0;
    else if (ai < 22.5f)                  bk = 1;
    else if (ai < 67.5f)                  bk = 2;
    else if (ai < 112.5f)                 bk = 3;
    else                                  bk = 4;
    bucket[idx] = bk;
}

// ---------------- Stage 3: NMS + double threshold -> bit-packed ----------------
// All 256 lanes stay active (no early return) so __ballot covers the full wave.
__global__ void k_nms(const float* __restrict__ mag,
                      const unsigned char* __restrict__ bucket,
                      unsigned long long* __restrict__ Sp,
                      unsigned long long* __restrict__ Wp) {
    int idx = blockIdx.x * blockDim.x + threadIdx.x;
    int i = idx >> 10;
    int j = idx & (IW - 1);
    bool border = (i == 0) | (i == IH - 1) | (j == 0) | (j == IW - 1);
    int ci = border ? (IW + 1) : idx;  // in-range center for neighbor indexing
    float c = mag[idx];
    float n1, n2;
    switch (bucket[idx]) {
        case 0:  n1 = mag[ci - 1];       n2 = mag[ci + 1];       break;
        case 2:  n1 = mag[ci - IW - 1];  n2 = mag[ci + IW + 1];  break;
        case 4:  n1 = mag[ci - IW + 1];  n2 = mag[ci + IW - 1];  break;
        default: n1 = mag[ci - IW];      n2 = mag[ci + IW];      break;
    }
    bool keep = (c >= n1) && (c >= n2);
    float supp = keep ? c : 0.f;
    bool sb = !border && (supp >= 50.f);
    bool wb = !border && (supp >= 20.f) && !(supp >= 50.f);
    unsigned long long bs = __ballot(sb);
    unsigned long long bw = __ballot(wb);
    if ((threadIdx.x & 63) == 0) {
        Sp[idx >> 6] = bs;  // bit b of word w  <=>  column w*64+b
        Wp[idx >> 6] = bw;
    }
}

// ---------------- Stage 4: single-wave bit-parallel hysteresis ----------------
// out[j] = S[j] | (W[j] & (seed[j] | out[j-1]));  seed = 8-neighbor OR
// (updated prev row, orig cur {j,j+1}, orig next row).  Lanes 0..15 each hold
// one 64-bit word of the row.  Column recurrence: Kogge-Stone inside the word,
// ballot + 16-bit Kogge-Stone for cross-word carry.  No barriers (one wave).
__global__ __launch_bounds__(64) void k_track(unsigned long long* __restrict__ Sp,
                                              const unsigned long long* __restrict__ Wp) {
    const int t = threadIdx.x;
    const bool act = (t < WPR);
    unsigned long long imask = ~0ull;              // interior-column mask
    if (t == 0)       imask = ~1ull;               // column 0
    if (t == WPR - 1) imask = ~(1ull << 63);       // column 1023

    unsigned long long prevU = act ? Sp[0 * WPR + t] : 0ull;  // updated row i-1
    unsigned long long Scur  = act ? Sp[1 * WPR + t] : 0ull;  // orig strong row i
    unsigned long long Snxt  = act ? Sp[2 * WPR + t] : 0ull;  // orig strong row i+1
    unsigned long long Wcur  = act ? Wp[1 * WPR + t] : 0ull;  // weak row i

    for (int i = 1; i <= IH - 2; ++i) {
        // prefetch next iteration's rows (consumed after full row body)
        unsigned long long Snn = 0ull, Wnxt = 0ull;
        if (act && i < IH - 2) {
            Snn  = Sp[(i + 2) * WPR + t];
            Wnxt = Wp[(i + 1) * WPR + t];
        }
        // neighbor words (lane 16 holds 0, so right-edge pulls are naturally 0)
        unsigned long long Sr = __shfl(Scur, (t + 1) & 63, 64);
        unsigned long long Nl = __shfl(Snxt, (t - 1) & 63, 64);
        unsigned long long Nr = __shfl(Snxt, (t + 1) & 63, 64);
        unsigned long long Pl = __shfl(prevU, (t - 1) & 63, 64);
        unsigned long long Pr = __shfl(prevU, (t + 1) & 63, 64);
        if (t == 0) { Nl = 0ull; Pl = 0ull; }

        unsigned long long seed =
              prevU | (prevU << 1) | (Pl >> 63) | (prevU >> 1) | (Pr << 63)
            | Scur  | (Scur >> 1)  | (Sr << 63)
            | Snxt  | (Snxt << 1)  | (Nl >> 63) | (Snxt >> 1) | (Nr << 63);

        unsigned long long P = Wcur & imask;
        unsigned long long G = Scur | (P & seed);

        #pragma unroll
        for (int k = 1; k <= 32; k <<= 1) {  // in-word carry-lookahead
            G |= P & (G << k);
            P &= (P << k);
        }
        unsigned long long gm = __ballot((bool)((G >> 63) & 1ull));
        unsigned long long pm = __ballot((bool)((P >> 63) & 1ull));
        #pragma unroll
        for (int k = 1; k <= 8; k <<= 1) {   // cross-word carry-lookahead
            gm |= pm & (gm << k);
            pm &= (pm << k);
        }
        bool cin = ((gm << 1) >> t) & 1ull;  // carry into word t = carry-out of t-1
        unsigned long long out = G | (cin ? P : 0ull);

        if (act) Sp[i * WPR + t] = out;
        prevU = out;
        Scur = Snxt;
        Snxt = Snn;
        Wcur = Wnxt;
    }
}

// ---------------- Stage 5: unpack bits -> float output ----------------
__global__ void k_unpack(const unsigned long long* __restrict__ Sp,
                         float* __restrict__ out) {
    int idx = blockIdx.x * blockDim.x + threadIdx.x;
    if (idx >= NPIX) return;
    out[idx] = ((Sp[idx >> 6] >> (idx & 63)) & 1ull) ? 1.f : 0.f;
}

extern "C" void kernel_launch(void* const* d_in, const int* in_sizes, int n_in,
                              void* d_out, int out_size, void* d_ws, size_t ws_size,
                              hipStream_t stream) {
    const float* x = (const float*)d_in[0];
    float* out = (float*)d_out;
    char* ws = (char*)d_ws;

    float* gray             = (float*)(ws);
    float* mag              = (float*)(ws + 4u * 1024u * 1024u);
    unsigned char* bkt      = (unsigned char*)(ws + 8u * 1024u * 1024u);
    unsigned long long* Sp  = (unsigned long long*)(ws + 9u * 1024u * 1024u);
    unsigned long long* Wp  = (unsigned long long*)(ws + 9u * 1024u * 1024u + 128u * 1024u);

    dim3 blk(256);
    dim3 grd((NPIX + 255) / 256);
    k_gray<<<grd, blk, 0, stream>>>(x, gray);
    k_sobel<<<grd, blk, 0, stream>>>(gray, mag, bkt);
    k_nms<<<grd, blk, 0, stream>>>(mag, bkt, Sp, Wp);
    k_track<<<1, 64, 0, stream>>>(Sp, Wp);
    k_unpack<<<grd, blk, 0, stream>>>(Sp, out);
}

// Round 3
// 414.397 us; speedup vs baseline: 4.6671x; 1.0806x over previous
//
#include <hip/hip_runtime.h>
#include <math.h>

#define IH 1024
#define IW 1024
#define NPIX (IH * IW)
#define WPR 16  // 64-bit words per row
#define PADROWS 1026  // 2 zero rows of padding for prefetch overrun

// ---------------- Stage 1+2 fused: gray -> Sobel -> mag + bucket ----------------
__global__ __launch_bounds__(256) void k_gray_sobel(const float* __restrict__ x,
                                                    float* __restrict__ mag,
                                                    unsigned char* __restrict__ bucket) {
    __shared__ float g[18][19];
    int bx = blockIdx.x & 63, by = blockIdx.x >> 6;
    int tid = threadIdx.x;
    for (int e = tid; e < 18 * 18; e += 256) {
        int ly = e / 18, lx = e - ly * 18;
        int gy = by * 16 - 1 + ly, gxc = bx * 16 - 1 + lx;
        float v = 0.f;
        if (gy >= 0 && gy < IH && gxc >= 0 && gxc < IW) {
            int p = gy * IW + gxc;
            float r = x[p], gg = x[NPIX + p], b = x[2 * NPIX + p];
            v = __fadd_rn(__fadd_rn(__fmul_rn(r, 0.2989f), __fmul_rn(gg, 0.587f)),
                          __fmul_rn(b, 0.114f));
        }
        g[ly][lx] = v;
    }
    __syncthreads();
    int ly = tid >> 4, lx = tid & 15;
    int i = by * 16 + ly, j = bx * 16 + lx;
    int idx = i * IW + j;
    float a00 = g[ly][lx],   a01 = g[ly][lx+1],   a02 = g[ly][lx+2];
    float a10 = g[ly+1][lx],                      a12 = g[ly+1][lx+2];
    float a20 = g[ly+2][lx], a21 = g[ly+2][lx+1], a22 = g[ly+2][lx+2];

    float gx = __fmul_rn(-1.f, a00);
    gx = __fadd_rn(gx, a02);
    gx = __fadd_rn(gx, __fmul_rn(-2.f, a10));
    gx = __fadd_rn(gx, __fmul_rn(2.f, a12));
    gx = __fadd_rn(gx, __fmul_rn(-1.f, a20));
    gx = __fadd_rn(gx, a22);

    float gy = a00;
    gy = __fadd_rn(gy, __fmul_rn(2.f, a01));
    gy = __fadd_rn(gy, a02);
    gy = __fadd_rn(gy, __fmul_rn(-1.f, a20));
    gy = __fadd_rn(gy, __fmul_rn(-2.f, a21));
    gy = __fadd_rn(gy, __fmul_rn(-1.f, a22));

    float m = __fsqrt_rn(__fadd_rn(__fmul_rn(gx, gx), __fmul_rn(gy, gy)));
    mag[idx] = m;

    float ai = __fmul_rn(atan2f(gy, gx), 57.295779513082320876798154814105f);
    unsigned char bk;
    if (ai < -22.5f || ai >= 157.5f)      bk = 0;
    else if (ai < 22.5f)                  bk = 1;
    else if (ai < 67.5f)                  bk = 2;
    else if (ai < 112.5f)                 bk = 3;
    else                                  bk = 4;
    bucket[idx] = bk;
}

// ---------------- Stage 3: NMS + double threshold -> bit-packed ----------------
__global__ void k_nms(const float* __restrict__ mag,
                      const unsigned char* __restrict__ bucket,
                      unsigned long long* __restrict__ Sp,
                      unsigned long long* __restrict__ Wp) {
    int idx = blockIdx.x * blockDim.x + threadIdx.x;
    int i = idx >> 10;
    int j = idx & (IW - 1);
    bool border = (i == 0) | (i == IH - 1) | (j == 0) | (j == IW - 1);
    int ci = border ? (IW + 1) : idx;
    float c = mag[idx];
    float n1, n2;
    switch (bucket[idx]) {
        case 0:  n1 = mag[ci - 1];       n2 = mag[ci + 1];       break;
        case 2:  n1 = mag[ci - IW - 1];  n2 = mag[ci + IW + 1];  break;
        case 4:  n1 = mag[ci - IW + 1];  n2 = mag[ci + IW - 1];  break;
        default: n1 = mag[ci - IW];      n2 = mag[ci + IW];      break;
    }
    bool keep = (c >= n1) && (c >= n2);
    float supp = keep ? c : 0.f;
    bool sb = !border && (supp >= 50.f);
    bool wb = !border && (supp >= 20.f) && !(supp >= 50.f);
    unsigned long long bs = __ballot(sb);
    unsigned long long bw = __ballot(wb);
    if ((threadIdx.x & 63) == 0) {
        Sp[idx >> 6] = bs;
        Wp[idx >> 6] = bw;
    }
}

// ---------------- Stage 3.5: precompute horizontal expansions + zero padding ----------------
// Rx(S) = S | S>>1 | (rightword bit0)<<63      (cur-row seed term: S[j] | S[j+1])
// Hx(S) = Rx | S<<1 | (leftword bit63)>>63     (full 3-neighbor OR)
__global__ void k_prep(unsigned long long* __restrict__ Sp,
                       unsigned long long* __restrict__ Wp,
                       unsigned long long* __restrict__ Rx,
                       unsigned long long* __restrict__ Hx) {
    int idx = blockIdx.x * blockDim.x + threadIdx.x;
    int r = idx >> 4, w = idx & 15;
    if (r >= PADROWS) return;
    if (r >= IH) {  // zero the prefetch-overrun padding rows (ws is poisoned!)
        Sp[idx] = 0ull; Wp[idx] = 0ull; Rx[idx] = 0ull; Hx[idx] = 0ull;
        return;
    }
    unsigned long long S  = Sp[idx];
    unsigned long long Sl = (w > 0)  ? Sp[idx - 1] : 0ull;
    unsigned long long Sr = (w < 15) ? Sp[idx + 1] : 0ull;
    unsigned long long rx = S | (S >> 1) | (Sr << 63);
    unsigned long long hx = rx | (S << 1) | (Sl >> 63);
    Rx[idx] = rx;
    Hx[idx] = hx;
}

// ---------------- Stage 4: single-wave tracker, adder-carry formulation ----------------
// out[j] = G[j] | P[j] & out[j-1]  ==  carry chain of (A+B+cin), A=G|P, B=G.
// No shuffles, no LDS: cross-word/row-boundary bits move via ballot (SGPR).
__global__ __launch_bounds__(64) void k_track(unsigned long long* __restrict__ Sp,
                                              const unsigned long long* __restrict__ Wp,
                                              const unsigned long long* __restrict__ Rx,
                                              const unsigned long long* __restrict__ Hx) {
    const int t = threadIdx.x;
    const bool act = (t < WPR);
    const int tl = (t + 63) & 63;
    const int tr = (t + 1) & 63;

    unsigned long long prevU = 0ull;       // row 0 strong is all-zero
    unsigned long long m63p = 0ull, m0p = 0ull;

    unsigned long long Scur = act ? Sp[1 * WPR + t] : 0ull;
    unsigned long long Wcur = act ? Wp[1 * WPR + t] : 0ull;
    unsigned long long RxC  = act ? Rx[1 * WPR + t] : 0ull;
    unsigned long long HxN  = act ? Hx[2 * WPR + t] : 0ull;

    unsigned long long Sq = act ? Sp[2 * WPR + t] : 0ull;   // pipeline stage
    unsigned long long Wq = act ? Wp[2 * WPR + t] : 0ull;
    unsigned long long Rq = act ? Rx[2 * WPR + t] : 0ull;
    unsigned long long Hq = act ? Hx[3 * WPR + t] : 0ull;

    #pragma unroll 2
    for (int i = 1; i <= IH - 2; ++i) {
        // prefetch, consumed at end of iteration i+1 (depth-2 => L2 latency hidden)
        unsigned long long Sq2 = 0ull, Wq2 = 0ull, Rq2 = 0ull, Hq2 = 0ull;
        if (act) {
            Sq2 = Sp[(i + 2) * WPR + t];
            Wq2 = Wp[(i + 2) * WPR + t];
            Rq2 = Rx[(i + 2) * WPR + t];
            Hq2 = Hx[(i + 3) * WPR + t];
        }

        unsigned long long lt = (m63p >> tl) & 1ull;          // left word's bit63
        unsigned long long rt = (m0p  >> tr) & 1ull;          // right word's bit0
        unsigned long long hxp = prevU | (prevU << 1) | (prevU >> 1) | lt | (rt << 63);
        unsigned long long seed = hxp | RxC | HxN;

        unsigned long long P = Wcur;                          // borders already 0
        unsigned long long G = Scur | (P & seed);
        unsigned long long A = G | P;
        unsigned long long s1 = A + G;
        bool ov1 = s1 < A;                                    // word generates carry
        bool pst = (s1 == ~0ull);                             // word propagates carry
        unsigned long long gm = __ballot(ov1);
        unsigned long long pm = __ballot(pst);
        // cross-word carries via the same adder trick, in scalar regs
        unsigned long long aa = gm | pm;
        unsigned long long ss = aa + gm;
        unsigned long long cvw = ss ^ aa ^ gm;                // bit t = carry into word t
        unsigned long long cin = (cvw >> t) & 1ull;
        unsigned long long s2 = s1 + cin;
        unsigned long long ovb = (ov1 || (pst && cin)) ? (1ull << 63) : 0ull;
        unsigned long long out = ((s2 ^ A ^ G) >> 1) | ovb;

        if (act) Sp[i * WPR + t] = out;
        m63p = __ballot((out >> 63) & 1ull);
        m0p  = __ballot(out & 1ull);
        prevU = out;
        Scur = Sq; Wcur = Wq; RxC = Rq; HxN = Hq;
        Sq = Sq2; Wq = Wq2; Rq = Rq2; Hq = Hq2;
    }
}

// ---------------- Stage 5: unpack bits -> float ----------------
__global__ void k_unpack(const unsigned long long* __restrict__ Sp,
                         float* __restrict__ out) {
    int idx = blockIdx.x * blockDim.x + threadIdx.x;
    if (idx >= NPIX) return;
    out[idx] = ((Sp[idx >> 6] >> (idx & 63)) & 1ull) ? 1.f : 0.f;
}

extern "C" void kernel_launch(void* const* d_in, const int* in_sizes, int n_in,
                              void* d_out, int out_size, void* d_ws, size_t ws_size,
                              hipStream_t stream) {
    const float* x = (const float*)d_in[0];
    float* out = (float*)d_out;
    char* ws = (char*)d_ws;

    float* mag              = (float*)(ws);
    unsigned char* bkt      = (unsigned char*)(ws + 4u * 1024u * 1024u);
    unsigned long long* Sp  = (unsigned long long*)(ws + 5u * 1024u * 1024u);
    unsigned long long* Wp  = (unsigned long long*)(ws + 5u * 1024u * 1024u + 256u * 1024u);
    unsigned long long* Rx  = (unsigned long long*)(ws + 5u * 1024u * 1024u + 512u * 1024u);
    unsigned long long* Hx  = (unsigned long long*)(ws + 5u * 1024u * 1024u + 768u * 1024u);

    dim3 blk(256);
    dim3 grd((NPIX + 255) / 256);
    k_gray_sobel<<<4096, 256, 0, stream>>>(x, mag, bkt);
    k_nms<<<grd, blk, 0, stream>>>(mag, bkt, Sp, Wp);
    k_prep<<<(PADROWS * WPR + 255) / 256, 256, 0, stream>>>(Sp, Wp, Rx, Hx);
    k_track<<<1, 64, 0, stream>>>(Sp, Wp, Rx, Hx);
    k_unpack<<<grd, blk, 0, stream>>>(Sp, out);
}

// Round 4
// 224.804 us; speedup vs baseline: 8.6033x; 1.8434x over previous
//
#include <hip/hip_runtime.h>
#include <math.h>

#define IH 1024
#define IW 1024
#define NPIX (IH * IW)

// ---------------- Stage 1+2 fused: gray -> Sobel -> mag + bucket ----------------
__global__ __launch_bounds__(256) void k_gray_sobel(const float* __restrict__ x,
                                                    float* __restrict__ mag,
                                                    unsigned char* __restrict__ bucket) {
    __shared__ float g[18][19];
    int bx = blockIdx.x & 63, by = blockIdx.x >> 6;
    int tid = threadIdx.x;
    for (int e = tid; e < 18 * 18; e += 256) {
        int ly = e / 18, lx = e - ly * 18;
        int gy = by * 16 - 1 + ly, gxc = bx * 16 - 1 + lx;
        float v = 0.f;
        if (gy >= 0 && gy < IH && gxc >= 0 && gxc < IW) {
            int p = gy * IW + gxc;
            float r = x[p], gg = x[NPIX + p], b = x[2 * NPIX + p];
            v = __fadd_rn(__fadd_rn(__fmul_rn(r, 0.2989f), __fmul_rn(gg, 0.587f)),
                          __fmul_rn(b, 0.114f));
        }
        g[ly][lx] = v;
    }
    __syncthreads();
    int ly = tid >> 4, lx = tid & 15;
    int i = by * 16 + ly, j = bx * 16 + lx;
    int idx = i * IW + j;
    float a00 = g[ly][lx],   a01 = g[ly][lx+1],   a02 = g[ly][lx+2];
    float a10 = g[ly+1][lx],                      a12 = g[ly+1][lx+2];
    float a20 = g[ly+2][lx], a21 = g[ly+2][lx+1], a22 = g[ly+2][lx+2];

    float gx = __fmul_rn(-1.f, a00);
    gx = __fadd_rn(gx, a02);
    gx = __fadd_rn(gx, __fmul_rn(-2.f, a10));
    gx = __fadd_rn(gx, __fmul_rn(2.f, a12));
    gx = __fadd_rn(gx, __fmul_rn(-1.f, a20));
    gx = __fadd_rn(gx, a22);

    float gy = a00;
    gy = __fadd_rn(gy, __fmul_rn(2.f, a01));
    gy = __fadd_rn(gy, a02);
    gy = __fadd_rn(gy, __fmul_rn(-1.f, a20));
    gy = __fadd_rn(gy, __fmul_rn(-2.f, a21));
    gy = __fadd_rn(gy, __fmul_rn(-1.f, a22));

    float m = __fsqrt_rn(__fadd_rn(__fmul_rn(gx, gx), __fmul_rn(gy, gy)));
    mag[idx] = m;

    float ai = __fmul_rn(atan2f(gy, gx), 57.295779513082320876798154814105f);
    unsigned char bk;
    if (ai < -22.5f || ai >= 157.5f)      bk = 0;
    else if (ai < 22.5f)                  bk = 1;
    else if (ai < 67.5f)                  bk = 2;
    else if (ai < 112.5f)                 bk = 3;
    else                                  bk = 4;
    bucket[idx] = bk;
}

// ---------------- Stage 3: NMS + double threshold -> bit-packed ----------------
__global__ void k_nms(const float* __restrict__ mag,
                      const unsigned char* __restrict__ bucket,
                      unsigned long long* __restrict__ Sp,
                      unsigned long long* __restrict__ Wp) {
    int idx = blockIdx.x * blockDim.x + threadIdx.x;
    int i = idx >> 10;
    int j = idx & (IW - 1);
    bool border = (i == 0) | (i == IH - 1) | (j == 0) | (j == IW - 1);
    int ci = border ? (IW + 1) : idx;
    float c = mag[idx];
    float n1, n2;
    switch (bucket[idx]) {
        case 0:  n1 = mag[ci - 1];       n2 = mag[ci + 1];       break;
        case 2:  n1 = mag[ci - IW - 1];  n2 = mag[ci + IW + 1];  break;
        case 4:  n1 = mag[ci - IW + 1];  n2 = mag[ci + IW - 1];  break;
        default: n1 = mag[ci - IW];      n2 = mag[ci + IW];      break;
    }
    bool keep = (c >= n1) && (c >= n2);
    float supp = keep ? c : 0.f;
    bool sb = !border && (supp >= 50.f);
    bool wb = !border && (supp >= 20.f) && !(supp >= 50.f);
    unsigned long long bs = __ballot(sb);
    unsigned long long bw = __ballot(wb);
    if ((threadIdx.x & 63) == 0) {
        Sp[idx >> 6] = bs;
        Wp[idx >> 6] = bw;
    }
}

// ---------------- Stage 4: single-wave tracker, u32 words, depth-16 prefetch ----
// Row recurrence out[j] = G | P & out[j-1] as an adder carry chain (u32 words),
// cross-word carry via masked ballot masks + scalar adder.  Lanes 32-63 mirror
// lanes 0-31 (duplicate loads/stores to identical addresses are benign).
__global__ __launch_bounds__(64) void k_track(unsigned int* __restrict__ Sp,
                                              const unsigned int* __restrict__ Wp) {
    const int k = threadIdx.x & 31;   // word index within row (32 u32 words/row)

    unsigned int Spipe[16], Wpipe[16];
    Spipe[1] = 0u;
    #pragma unroll
    for (int d = 0; d < 15; ++d)   // S rows 2..16
        Spipe[(2 + d) & 15] = Sp[(2 + d) * 32 + k];
    #pragma unroll
    for (int d = 0; d < 16; ++d)   // W rows 1..16
        Wpipe[(1 + d) & 15] = Wp[(1 + d) * 32 + k];

    unsigned int SC = Sp[32 + k];                      // S row 1 (cur)
    unsigned long long mSC_lo = __ballot((SC & 1u) != 0u);
    unsigned int prevU = 0u;                            // updated row 0 = zeros
    unsigned int cin_prev = 0u;                         // carry-in bits of prev row
    unsigned long long mlo_prev = 0ull;                 // prev row out bit0 mask

    for (int b = 0; b < 64; ++b) {
        const int base = 1 + b * 16;
        #pragma unroll
        for (int d = 0; d < 16; ++d) {
            const int i = base + d;
            unsigned int SN = Spipe[(2 + d) & 15];      // S row i+1
            unsigned int Wc = Wpipe[(1 + d) & 15];      // W row i

            // prefetch rows i+16 (clamped; duplicates beyond the end are never
            // consumed by a storing body)
            int srow = i + 16; if (srow > 1023) srow = 1023;
            int wrow = i + 16; if (wrow > 1022) wrow = 1022;
            {
                const unsigned int* ps = Sp + srow * 32;   // uniform base (SGPR)
                const unsigned int* pw = Wp + wrow * 32;
                Spipe[(1 + d) & 15] = ps[k];
                Wpipe[(1 + d) & 15] = pw[k];
            }

            // static (original-data) seed terms, off the serial chain
            unsigned long long mSN_hi = __ballot((SN >> 31) != 0u);
            unsigned long long mSN_lo = __ballot((SN & 1u) != 0u);
            unsigned int ltN = ((unsigned int)(mSN_hi << 1) >> k) & 1u;
            unsigned int rtN = ((((unsigned int)(mSN_lo >> 1)) >> k) & 1u) << 31;
            unsigned int HxN = SN | (SN << 1) | (SN >> 1) | ltN | rtN;
            unsigned int rtC = ((((unsigned int)(mSC_lo >> 1)) >> k) & 1u) << 31;
            unsigned int RxC = SC | (SC >> 1) | rtC;
            unsigned int STAT = RxC | HxN;

            // dynamic seed from updated previous row
            unsigned int rtP = ((((unsigned int)(mlo_prev >> 1)) >> k) & 1u) << 31;
            unsigned int hxp = prevU | (prevU << 1) | (prevU >> 1) | cin_prev | rtP;
            unsigned int seed = hxp | STAT;

            // recurrence as adder carry chain
            unsigned int P = Wc;                        // border bits already 0
            unsigned int G = SC | (P & seed);
            unsigned int A = G | P;
            unsigned int AXG = A ^ G;
            unsigned int s1 = A + G;
            unsigned long long gm = __ballot(s1 < A) & 0xFFFFFFFFull;
            unsigned long long pm = __ballot(s1 == 0xFFFFFFFFu) & 0xFFFFFFFFull;
            unsigned long long G0 = __ballot((G & 1u) != 0u);
            unsigned long long P0 = __ballot((P & 1u) != 0u);
            unsigned long long aa = gm | pm;
            unsigned long long ss = aa + gm;
            unsigned long long cvw = ss ^ aa ^ gm;      // bit k = carry into word k
            unsigned int cin = (((unsigned int)cvw) >> k) & 1u;
            unsigned int ovb = ((((unsigned int)(cvw >> 1)) >> k) & 1u) << 31;
            unsigned int s2 = s1 + cin;
            unsigned int out = ((s2 ^ AXG) >> 1) | ovb;

            if (i <= 1022) {
                unsigned int* po = Sp + i * 32;
                po[k] = out;                            // lanes 32-63 duplicate: benign
            }

            mlo_prev = G0 | (P0 & cvw);
            cin_prev = cin;
            prevU = out;
            SC = SN;
            mSC_lo = mSN_lo;
        }
    }
}

// ---------------- Stage 5: unpack bits -> float ----------------
__global__ void k_unpack(const unsigned int* __restrict__ Sp,
                         float* __restrict__ out) {
    int idx = blockIdx.x * blockDim.x + threadIdx.x;
    if (idx >= NPIX) return;
    out[idx] = ((Sp[idx >> 5] >> (idx & 31)) & 1u) ? 1.f : 0.f;
}

extern "C" void kernel_launch(void* const* d_in, const int* in_sizes, int n_in,
                              void* d_out, int out_size, void* d_ws, size_t ws_size,
                              hipStream_t stream) {
    const float* x = (const float*)d_in[0];
    float* out = (float*)d_out;
    char* ws = (char*)d_ws;

    float* mag              = (float*)(ws);
    unsigned char* bkt      = (unsigned char*)(ws + 4u * 1024u * 1024u);
    unsigned long long* Sp  = (unsigned long long*)(ws + 5u * 1024u * 1024u);
    unsigned long long* Wp  = (unsigned long long*)(ws + 5u * 1024u * 1024u + 256u * 1024u);

    dim3 blk(256);
    dim3 grd((NPIX + 255) / 256);
    k_gray_sobel<<<4096, 256, 0, stream>>>(x, mag, bkt);
    k_nms<<<grd, blk, 0, stream>>>(mag, bkt, Sp, Wp);
    k_track<<<1, 64, 0, stream>>>((unsigned int*)Sp, (const unsigned int*)Wp);
    k_unpack<<<grd, blk, 0, stream>>>((const unsigned int*)Sp, out);
}

// Round 5
// 207.297 us; speedup vs baseline: 9.3298x; 1.0845x over previous
//
#include <hip/hip_runtime.h>
#include <math.h>

#define IH 1024
#define IW 1024
#define NPIX (IH * IW)

// ---------------- Stage 1+2 fused: gray -> Sobel -> mag + bucket ----------------
__global__ __launch_bounds__(256) void k_gray_sobel(const float* __restrict__ x,
                                                    float* __restrict__ mag,
                                                    unsigned char* __restrict__ bucket) {
    __shared__ float g[18][19];
    int bx = blockIdx.x & 63, by = blockIdx.x >> 6;
    int tid = threadIdx.x;
    for (int e = tid; e < 18 * 18; e += 256) {
        int ly = e / 18, lx = e - ly * 18;
        int gy = by * 16 - 1 + ly, gxc = bx * 16 - 1 + lx;
        float v = 0.f;
        if (gy >= 0 && gy < IH && gxc >= 0 && gxc < IW) {
            int p = gy * IW + gxc;
            float r = x[p], gg = x[NPIX + p], b = x[2 * NPIX + p];
            v = __fadd_rn(__fadd_rn(__fmul_rn(r, 0.2989f), __fmul_rn(gg, 0.587f)),
                          __fmul_rn(b, 0.114f));
        }
        g[ly][lx] = v;
    }
    __syncthreads();
    int ly = tid >> 4, lx = tid & 15;
    int i = by * 16 + ly, j = bx * 16 + lx;
    int idx = i * IW + j;
    float a00 = g[ly][lx],   a01 = g[ly][lx+1],   a02 = g[ly][lx+2];
    float a10 = g[ly+1][lx],                      a12 = g[ly+1][lx+2];
    float a20 = g[ly+2][lx], a21 = g[ly+2][lx+1], a22 = g[ly+2][lx+2];

    float gx = __fmul_rn(-1.f, a00);
    gx = __fadd_rn(gx, a02);
    gx = __fadd_rn(gx, __fmul_rn(-2.f, a10));
    gx = __fadd_rn(gx, __fmul_rn(2.f, a12));
    gx = __fadd_rn(gx, __fmul_rn(-1.f, a20));
    gx = __fadd_rn(gx, a22);

    float gy = a00;
    gy = __fadd_rn(gy, __fmul_rn(2.f, a01));
    gy = __fadd_rn(gy, a02);
    gy = __fadd_rn(gy, __fmul_rn(-1.f, a20));
    gy = __fadd_rn(gy, __fmul_rn(-2.f, a21));
    gy = __fadd_rn(gy, __fmul_rn(-1.f, a22));

    float m = __fsqrt_rn(__fadd_rn(__fmul_rn(gx, gx), __fmul_rn(gy, gy)));
    mag[idx] = m;

    float ai = __fmul_rn(atan2f(gy, gx), 57.295779513082320876798154814105f);
    unsigned char bk;
    if (ai < -22.5f || ai >= 157.5f)      bk = 0;
    else if (ai < 22.5f)                  bk = 1;
    else if (ai < 67.5f)                  bk = 2;
    else if (ai < 112.5f)                 bk = 3;
    else                                  bk = 4;
    bucket[idx] = bk;
}

// ---------------- Stage 3: NMS + double threshold -> bit-packed ----------------
__global__ void k_nms(const float* __restrict__ mag,
                      const unsigned char* __restrict__ bucket,
                      unsigned long long* __restrict__ Sp,
                      unsigned long long* __restrict__ Wp) {
    int idx = blockIdx.x * blockDim.x + threadIdx.x;
    int i = idx >> 10;
    int j = idx & (IW - 1);
    bool border = (i == 0) | (i == IH - 1) | (j == 0) | (j == IW - 1);
    int ci = border ? (IW + 1) : idx;
    float c = mag[idx];
    float n1, n2;
    switch (bucket[idx]) {
        case 0:  n1 = mag[ci - 1];       n2 = mag[ci + 1];       break;
        case 2:  n1 = mag[ci - IW - 1];  n2 = mag[ci + IW + 1];  break;
        case 4:  n1 = mag[ci - IW + 1];  n2 = mag[ci + IW - 1];  break;
        default: n1 = mag[ci - IW];      n2 = mag[ci + IW];      break;
    }
    bool keep = (c >= n1) && (c >= n2);
    float supp = keep ? c : 0.f;
    bool sb = !border && (supp >= 50.f);
    bool wb = !border && (supp >= 20.f) && !(supp >= 50.f);
    unsigned long long bs = __ballot(sb);
    unsigned long long bw = __ballot(wb);
    if ((threadIdx.x & 63) == 0) {
        Sp[idx >> 6] = bs;
        Wp[idx >> 6] = bw;
    }
}

// ---------------- Stage 4: single-wave tracker ----------------
// u32 words (lanes 32-63 mirror 0-31).  Row recurrence out = G | P&(out>>1col)
// as hardware adder carry chain; cross-word carry via masked ballots + scalar
// adder.  Pipeline slots are NAMED scalars (literal indices) so they live in
// VGPRs, not scratch.  Off-chain work (next row's static seed, prefetch, store)
// is fenced between the ballots and their SALU consumers to cover the hazard.
#define TRACK_BODY(d, SRD, SWR, WRD) {                                          \
    const int i = base + d;                                                     \
    /* ---- serial chain head ---- */                                           \
    unsigned int hxp = (prevU << 1) | prevU | ((prevU >> 1) | crp);             \
    unsigned int seed = hxp | STAT;                                             \
    unsigned int P = WRD;                                                       \
    unsigned int G = SCc | (P & seed);                                          \
    unsigned int A = G | P;                                                     \
    unsigned int AXG = A ^ G;                                                   \
    unsigned int s1v = A + G;                                                   \
    unsigned long long gm = __ballot(s1v < A) & 0xFFFFFFFFull;                  \
    unsigned long long pm = __ballot(s1v == 0xFFFFFFFFu) & 0xFFFFFFFFull;       \
    unsigned long long G0 = __ballot((G & 1u) != 0u);                           \
    unsigned long long P0 = __ballot((P & 1u) != 0u);                           \
    __builtin_amdgcn_sched_barrier(0);                                          \
    /* ---- independent: next row's static seed + prefetch + store ---- */      \
    unsigned int SN2 = SRD;                                                     \
    unsigned long long mhi = __ballot((SN2 >> 31) != 0u);                       \
    unsigned long long mlo2 = __ballot((SN2 & 1u) != 0u);                       \
    unsigned int ltN = (((unsigned int)(mhi << 1)) >> k) & 1u;                  \
    unsigned int rtN = ((((unsigned int)(mlo2 >> 1)) >> k) & 1u) << 31;         \
    unsigned int rtA = ((((unsigned int)(mSA_lo >> 1)) >> k) & 1u) << 31;       \
    unsigned int nSTAT = SA | (SA >> 1) | rtA                                   \
                       | SN2 | (SN2 << 1) | (SN2 >> 1) | ltN | rtN;             \
    { int srow = i + 17; if (srow > 1023) srow = 1023;                          \
      int wrow = i + 16; if (wrow > 1023) wrow = 1023;                          \
      SWR = Sp[srow * 32 + k];                                                  \
      WRD = Wp[wrow * 32 + k]; }                                                \
    if (i >= 2 && i <= 1023) Sp[(i - 1) * 32 + k] = prevU;                      \
    __builtin_amdgcn_sched_barrier(0);                                          \
    /* ---- resolve cross-word carries ---- */                                  \
    unsigned long long aa = gm | pm;                                            \
    unsigned long long ssum = aa + gm;                                          \
    unsigned long long cvw = ssum ^ aa ^ gm;                                    \
    unsigned long long mlo_o = G0 | (P0 & cvw);                                 \
    unsigned int cvw_lo = (unsigned int)cvw;                                    \
    unsigned int cvw_hi = (unsigned int)(cvw >> 1);                             \
    unsigned int shml = (unsigned int)(mlo_o >> 1);                             \
    unsigned int cin = (cvw_lo >> k) & 1u;                                      \
    unsigned int ovb = ((cvw_hi >> k) & 1u) << 31;                              \
    unsigned int s2 = s1v + cin;                                                \
    unsigned int outv = ((s2 ^ AXG) >> 1) | ovb;                                \
    unsigned int rtP = ((shml >> k) & 1u) << 31;                                \
    crp = cin | rtP;                                                            \
    prevU = outv;                                                               \
    SCc = SA; SA = SN2; mSA_lo = mlo2; STAT = nSTAT;                            \
}

__global__ __launch_bounds__(64) void k_track(unsigned int* __restrict__ Sp,
                                              const unsigned int* __restrict__ Wp) {
    const int k = threadIdx.x & 31;

    unsigned int ss0, ss1, ss2, ss3, ss4, ss5, ss6, ss7,
                 ss8, ss9, ss10, ss11, ss12, ss13, ss14, ss15;
    unsigned int ww0, ww1, ww2, ww3, ww4, ww5, ww6, ww7,
                 ww8, ww9, ww10, ww11, ww12, ww13, ww14, ww15;

    // preamble: S rows 1,2 in registers; S rows 3..17 in slots r&15; W rows 1..16
    unsigned int SCc = Sp[1 * 32 + k];
    unsigned int SA  = Sp[2 * 32 + k];
    ss3 = Sp[3 * 32 + k];   ss4 = Sp[4 * 32 + k];   ss5 = Sp[5 * 32 + k];
    ss6 = Sp[6 * 32 + k];   ss7 = Sp[7 * 32 + k];   ss8 = Sp[8 * 32 + k];
    ss9 = Sp[9 * 32 + k];   ss10 = Sp[10 * 32 + k]; ss11 = Sp[11 * 32 + k];
    ss12 = Sp[12 * 32 + k]; ss13 = Sp[13 * 32 + k]; ss14 = Sp[14 * 32 + k];
    ss15 = Sp[15 * 32 + k]; ss0 = Sp[16 * 32 + k];  ss1 = Sp[17 * 32 + k];
    ss2 = 0u;
    ww1 = Wp[1 * 32 + k];   ww2 = Wp[2 * 32 + k];   ww3 = Wp[3 * 32 + k];
    ww4 = Wp[4 * 32 + k];   ww5 = Wp[5 * 32 + k];   ww6 = Wp[6 * 32 + k];
    ww7 = Wp[7 * 32 + k];   ww8 = Wp[8 * 32 + k];   ww9 = Wp[9 * 32 + k];
    ww10 = Wp[10 * 32 + k]; ww11 = Wp[11 * 32 + k]; ww12 = Wp[12 * 32 + k];
    ww13 = Wp[13 * 32 + k]; ww14 = Wp[14 * 32 + k]; ww15 = Wp[15 * 32 + k];
    ww0 = Wp[16 * 32 + k];

    unsigned long long mSC_lo = __ballot((SCc & 1u) != 0u);
    unsigned long long mSA_lo = __ballot((SA & 1u) != 0u);
    unsigned long long mSA_hi = __ballot((SA >> 31) != 0u);
    unsigned int rtC = ((((unsigned int)(mSC_lo >> 1)) >> k) & 1u) << 31;
    unsigned int ltA = (((unsigned int)(mSA_hi << 1)) >> k) & 1u;
    unsigned int rtA0 = ((((unsigned int)(mSA_lo >> 1)) >> k) & 1u) << 31;
    unsigned int STAT = SCc | (SCc >> 1) | rtC
                      | SA | (SA << 1) | (SA >> 1) | ltA | rtA0;
    unsigned int prevU = 0u, crp = 0u;

    #pragma unroll 1
    for (int b = 0; b < 64; ++b) {
        const int base = 1 + b * 16;
        TRACK_BODY(0,  ss3,  ss2,  ww1)
        TRACK_BODY(1,  ss4,  ss3,  ww2)
        TRACK_BODY(2,  ss5,  ss4,  ww3)
        TRACK_BODY(3,  ss6,  ss5,  ww4)
        TRACK_BODY(4,  ss7,  ss6,  ww5)
        TRACK_BODY(5,  ss8,  ss7,  ww6)
        TRACK_BODY(6,  ss9,  ss8,  ww7)
        TRACK_BODY(7,  ss10, ss9,  ww8)
        TRACK_BODY(8,  ss11, ss10, ww9)
        TRACK_BODY(9,  ss12, ss11, ww10)
        TRACK_BODY(10, ss13, ss12, ww11)
        TRACK_BODY(11, ss14, ss13, ww12)
        TRACK_BODY(12, ss15, ss14, ww13)
        TRACK_BODY(13, ss0,  ss15, ww14)
        TRACK_BODY(14, ss1,  ss0,  ww15)
        TRACK_BODY(15, ss2,  ss1,  ww0)
    }
}

// ---------------- Stage 5: unpack bits -> float ----------------
__global__ void k_unpack(const unsigned int* __restrict__ Sp,
                         float* __restrict__ out) {
    int idx = blockIdx.x * blockDim.x + threadIdx.x;
    if (idx >= NPIX) return;
    out[idx] = ((Sp[idx >> 5] >> (idx & 31)) & 1u) ? 1.f : 0.f;
}

extern "C" void kernel_launch(void* const* d_in, const int* in_sizes, int n_in,
                              void* d_out, int out_size, void* d_ws, size_t ws_size,
                              hipStream_t stream) {
    const float* x = (const float*)d_in[0];
    float* out = (float*)d_out;
    char* ws = (char*)d_ws;

    float* mag              = (float*)(ws);
    unsigned char* bkt      = (unsigned char*)(ws + 4u * 1024u * 1024u);
    unsigned long long* Sp  = (unsigned long long*)(ws + 5u * 1024u * 1024u);
    unsigned long long* Wp  = (unsigned long long*)(ws + 5u * 1024u * 1024u + 256u * 1024u);

    dim3 blk(256);
    dim3 grd((NPIX + 255) / 256);
    k_gray_sobel<<<4096, 256, 0, stream>>>(x, mag, bkt);
    k_nms<<<grd, blk, 0, stream>>>(mag, bkt, Sp, Wp);
    k_track<<<1, 64, 0, stream>>>((unsigned int*)Sp, (const unsigned int*)Wp);
    k_unpack<<<grd, blk, 0, stream>>>((const unsigned int*)Sp, out);
}